// Round 10
// baseline (169.729 us; speedup 1.0000x reference)
//
#include <hip/hip_runtime.h>

// SAModule (PointNet++ SA), fused f32-input kernel. R15:
//  - R14 post-mortem: VALU busy -4us but duration flat => not VALU-issue-bound.
//    Plateau signature (issue util ~50% on all pipes, insensitive to occupancy/schedule/
//    instruction cuts, R7's compact-loop 91us never beaten by unrolled variants) points to
//    INSTRUCTION FETCH: R11+ fully-unrolled ~40KB hot code >> I$, and 16 waves drift
//    through different phases so the concurrent footprint is the whole kernel.
//  - R15 = R14 logic with code shrunk ~4x: GEMM N-step loops rolled (#pragma unroll 1,
//    s+=2 bodies for even/odd prefetch regs; ki loops stay unrolled for static reg
//    indexing), per-step addresses = base + s*256 + precomputed ofs[ki], overfetch/
//    clamp instead of tail guards, phase-A point loop rolled.

typedef unsigned short u16;
typedef unsigned int u32;
typedef unsigned long long u64;
typedef __bf16 bf16x8 __attribute__((ext_vector_type(8)));
typedef float floatx4 __attribute__((ext_vector_type(4)));

#define PCLOUD 4096
#define DIN    64
#define MCENT  8192
#define KNBR   32
#define CAP    448
#define WAVES  8

// smem map (65536 B): sA = 256 rows x 256B. phase A/B overlay (dead before gather):
#define OFF_LIST  0        // u64[8][CAP] = 28672
#define OFF_HIST  28672    // u32[8][32]  = 1024
#define OFF_NBRL  29696    // int[8][32]  = 1024
#define OFF_CNT   30720    // int[8] acnt | int[8] cnt2
#define OFF_CEN   30784    // float4[8] centers (x,y,z,|c|^2)
#define OFF_BCL   30912    // int[8] cloud ids

__device__ inline u16 f2bf(float f) {          // RNE, no scrub (inputs finite)
    u32 b = __float_as_uint(f);
    b += 0x7fffu + ((b >> 16) & 1u);
    return (u16)(b >> 16);
}
__device__ inline u32 cvtpk(float a, float b) {  // packed {bf16(a), bf16(b)<<16}, RNE
    u32 r;
    asm("v_cvt_pk_bf16_f32 %0, %1, %2" : "=v"(r) : "v"(a), "v"(b));
    return r;
}
__device__ inline u64 wave_min_u64(u64 v) {
    #pragma unroll
    for (int off = 32; off; off >>= 1) {
        u64 o = __shfl_xor((unsigned long long)v, off);
        if (o < v) v = o;
    }
    return v;
}
// density-equalized bucket over raw-bits keys (d2 >= 0): count/bucket ~ const, monotone.
__device__ inline int key_bucket(u64 k) {
    float d2 = __uint_as_float((u32)(k >> 32));
    float t = d2 * 25.0f;                              // d2/R2, [0,1]
    float b = 32.0f * t * __builtin_sqrtf(t);          // 32 * t^1.5
    int bi = (int)b;
    return bi > 31 ? 31 : bi;
}

// ---- prep: weights -> bf16 B-fragment images in ws (consumed directly from L2) ----
// 32 contiguous 4KB blocks of 16 cols each: blk 0..7 = W1, 8..15 = W2, 16..31 = W3.
// blk layout (256 uint4): chunk[n*16 + (kc^(n&7))] = {bf16 W[kc*8+j][col0+n], j=0..7}
__global__ void prep_kernel(const float* __restrict__ W1, const float* __restrict__ W2,
                            const float* __restrict__ W3, uint4* __restrict__ ws) {
    int t = blockIdx.x * 256 + threadIdx.x;   // 0..8191
    int g = t >> 11, r = t & 2047;
    int n = r >> 4, kc = r & 15;
    const float* W; int rs, n0, krows;
    if (g == 0)      { W = W1; rs = 128; n0 = 0;   krows = 67;  }
    else if (g == 1) { W = W2; rs = 128; n0 = 0;   krows = 128; }
    else if (g == 2) { W = W3; rs = 256; n0 = 0;   krows = 128; }
    else             { W = W3; rs = 256; n0 = 128; krows = 128; }
    u16 e[8];
    #pragma unroll
    for (int j = 0; j < 8; j++) {
        int k = kc * 8 + j;
        e[j] = (k < krows) ? f2bf(W[(size_t)k * rs + n0 + n]) : (u16)0;
    }
    ws[(g << 11) + (n << 4) + (kc ^ (n & 7))] = *(const uint4*)e;
}

// Workspace-less fallback: gather the column from W in f32 and pack (correctness path).
__device__ __forceinline__ uint4 ldB_fb(const float* __restrict__ W, int rs, int col,
                                        int cb, int krows) {
    u16 e[8];
    #pragma unroll
    for (int j = 0; j < 8; j++) {
        int k = cb * 8 + j;
        e[j] = (k < krows) ? f2bf(W[(size_t)k * rs + col]) : (u16)0;
    }
    return *(const uint4*)e;
}

// Lean hit push: clamp d2>=0 (self-point FMA noise), raw-bits monotone key.
__device__ __forceinline__ void push_hit(int c, float d2, int j,
                                         int* acnt, u64* lists) {
    int p = atomicAdd(&acnt[c], 1);
    u64 key = ((u64)__float_as_uint(fmaxf(d2, 0.0f)) << 32) | (u32)j;
    if (p < CAP) lists[c * CAP + p] = key;
}

template <bool WS>
__global__ __launch_bounds__(512, 4) void sa_kernel(
    const float* __restrict__ x, const float* __restrict__ pos,
    const int* __restrict__ batch, const int* __restrict__ idx,
    const float* __restrict__ W1, const float* __restrict__ b1,
    const float* __restrict__ W2, const float* __restrict__ b2,
    const float* __restrict__ W3, const float* __restrict__ b3,
    const uint4* __restrict__ ws4, float* __restrict__ out) {
    __shared__ __align__(16) char smem[65536];
    u64*  lists = (u64*)(smem + OFF_LIST);
    u32*  hist  = (u32*)(smem + OFF_HIST);
    int*  nbrl  = (int*)(smem + OFF_NBRL);
    int*  acnt  = (int*)(smem + OFF_CNT);
    int*  cnt2  = (int*)(smem + OFF_CNT + 32);
    float4* cen = (float4*)(smem + OFF_CEN);
    int*  bcls  = (int*)(smem + OFF_BCL);
    uint4* sA4  = (uint4*)smem;

    int tid = threadIdx.x, w = tid >> 6, l = tid & 63;
    int bid = blockIdx.x;
    int m0 = ((bid & 7) << 10) + ((bid >> 3) << 3);   // XCD-friendly: bid%8 ~ cloud
    int m = m0 + w;
    int ic = idx[m] & (8 * PCLOUD - 1);
    float cx = pos[ic * 3], cy = pos[ic * 3 + 1], cz = pos[ic * 3 + 2];
    float sc = __fadd_rn(__fadd_rn(__fmul_rn(cx, cx), __fmul_rn(cy, cy)), __fmul_rn(cz, cz));
    int bcl = batch[ic] & 7;
    int base = bcl << 12;
    const float R2 = 0.04f;

    if (l == 0) { cen[w] = make_float4(cx, cy, cz, sc); bcls[w] = bcl; }
    if (tid < WAVES) { acnt[tid] = 0; cnt2[tid] = 0; }
    if (l == 1) {
        float* o1 = out + MCENT * 256;
        o1[m * 3] = cx; o1[m * 3 + 1] = cy; o1[m * 3 + 2] = cz;
        (o1 + MCENT * 3)[m] = (float)bcl;
    }
    __syncthreads();

    // ---- phase A: cooperative scan, float4 loads, FMA-contracted tests vs 8 centers ----
    bool uni = true;
    #pragma unroll
    for (int cc = 1; cc < WAVES; cc++) uni = uni && (bcls[cc] == bcls[0]);
    if (uni) {
        float4 cw[WAVES];
        float nx[WAVES], ny[WAVES], nz[WAVES];
        #pragma unroll
        for (int cc = 0; cc < WAVES; cc++) {
            cw[cc] = cen[cc];
            nx[cc] = -2.0f * cw[cc].x; ny[cc] = -2.0f * cw[cc].y; nz[cc] = -2.0f * cw[cc].z;
        }
        int jb = bcls[0] << 12;
        const float4* pb4 = (const float4*)(pos + (size_t)jb * 3);

#define TESTP(PX, PY, PZ, J) { \
    float sp = __builtin_fmaf((PX), (PX), __builtin_fmaf((PY), (PY), (PZ) * (PZ))); \
    _Pragma("unroll") \
    for (int cc = 0; cc < WAVES; cc++) { \
        float d2 = __builtin_fmaf(nx[cc], (PX), __builtin_fmaf(ny[cc], (PY), \
                   __builtin_fmaf(nz[cc], (PZ), cw[cc].w + sp))); \
        if (d2 <= R2) push_hit(cc, d2, (J), acnt, lists); \
    } }

        #pragma unroll 1
        for (int it = 0; it < 2; it++) {
            int tq = it * 512 + tid;                   // quad-point index 0..1023
            float4 q0 = pb4[tq * 3], q1 = pb4[tq * 3 + 1], q2 = pb4[tq * 3 + 2];
            int j0 = jb + tq * 4;
            TESTP(q0.x, q0.y, q0.z, j0)
            TESTP(q0.w, q1.x, q1.y, j0 + 1)
            TESTP(q1.z, q1.w, q2.x, j0 + 2)
            TESTP(q2.y, q2.z, q2.w, j0 + 3)
        }
#undef TESTP
    } else {
        // rare mixed-cloud block: per-wave scan of own cloud from global (FMA form)
        float nx = -2.0f * cx, ny = -2.0f * cy, nz = -2.0f * cz;
        for (int t = l; t < PCLOUD; t += 64) {
            int j = base + t;
            float px = pos[j * 3], py = pos[j * 3 + 1], pz = pos[j * 3 + 2];
            float sp = __builtin_fmaf(px, px, __builtin_fmaf(py, py, pz * pz));
            float d2 = __builtin_fmaf(nx, px, __builtin_fmaf(ny, py,
                       __builtin_fmaf(nz, pz, sc + sp)));
            if (d2 <= R2) push_hit(w, d2, j, acnt, lists);
        }
    }
    __syncthreads();   // cross-wave list visibility

    int c = acnt[w];
    u64* mylist = lists + w * CAP;

    // ---- phase B: select the 32 smallest (d2,idx) keys (set only; order free) ----
    int selj = -1;
    if (c <= KNBR) {
        if (l < c) selj = (int)(u32)mylist[l];
    } else if (c <= CAP) {
        u64 kk[7];
        int bk[7];
        if (l < 32) hist[w * 32 + l] = 0;              // same-wave LDS: ordered
        #pragma unroll
        for (int i = 0; i < 7; i++) kk[i] = (l + i * 64 < c) ? mylist[l + i * 64] : ~0ull;
        #pragma unroll
        for (int i = 0; i < 7; i++) {                  // build d2 histogram (this wave only)
            bk[i] = 32;
            if (kk[i] != ~0ull) {
                bk[i] = key_bucket(kk[i]);
                atomicAdd(&hist[w * 32 + bk[i]], 1u);
            }
        }
        int hv = (l < 32) ? (int)hist[w * 32 + l] : 0; // atomics above are same-wave: ordered
        #pragma unroll
        for (int off = 1; off <= 16; off <<= 1) {   // inclusive scan, lanes 0..31
            int o = __shfl_up(hv, off);
            if (l >= off) hv += o;
        }
        u64 ge = __ballot((l < 32) && (hv >= KNBR));
        int B = __ffsll((unsigned long long)ge) - 1;        // threshold bucket
        int S = (B == 0) ? 0 : __shfl(hv, B - 1);           // count strictly below B
        #pragma unroll
        for (int i = 0; i < 7; i++) {                       // bulk-select below B
            if (kk[i] != ~0ull) {
                if (bk[i] < B) { int p = atomicAdd(&cnt2[w], 1); nbrl[w * 32 + p] = (int)(u32)kk[i]; }
                if (bk[i] != B) kk[i] = ~0ull;              // keep only bucket-B keys
            }
        }
        int need = KNBR - S;                                // equalized buckets: ~1-4 rounds
        u64 last = 0;
        for (int r = 0; r < need; r++) {
            u64 mn = ~0ull;
            #pragma unroll
            for (int i = 0; i < 7; i++) if (kk[i] > last && kk[i] < mn) mn = kk[i];
            mn = wave_min_u64(mn);
            if (l == 0) nbrl[w * 32 + S + r] = (int)(u32)mn;
            last = mn;
        }
        if (l < KNBR) selj = nbrl[w * 32 + l];
    } else {
        // overflow fallback (never taken for uniform data): streaming 32-round argmin
        float nx = -2.0f * cx, ny = -2.0f * cy, nz = -2.0f * cz;
        u64 last = 0;
        for (int r = 0; r < KNBR; r++) {
            u64 mn = ~0ull;
            for (int t = l; t < PCLOUD; t += 64) {
                int j = base + t;
                float px = pos[j * 3], py = pos[j * 3 + 1], pz = pos[j * 3 + 2];
                float sp = __builtin_fmaf(px, px, __builtin_fmaf(py, py, pz * pz));
                float d2 = __builtin_fmaf(nx, px, __builtin_fmaf(ny, py,
                           __builtin_fmaf(nz, pz, sc + sp)));
                if (d2 <= R2) {
                    u64 kf = ((u64)__float_as_uint(fmaxf(d2, 0.0f)) << 32) | (u32)j;
                    if (kf > last && kf < mn) mn = kf;
                }
            }
            mn = wave_min_u64(mn);
            if (l == r) selj = (int)(u32)mn;
            last = mn;
        }
    }
    // duplicate-pad: rows beyond the valid count take lane-0's neighbor (MAX-invariant).
    {
        int s0 = __shfl(selj, 0);
        if (selj < 0) selj = s0;
    }
    __syncthreads();   // LAST barrier: lists/hist dead; sA becomes the (wave-private) A-tile

    // ---- gather 32 feat rows per wave (XOR 16B-chunk swizzle); rows are wave-private. ----
    {
        int h = l & 1, rl = l >> 1;
        int row = w * 32 + rl;
        int j = __shfl(selj, rl);
        int xv = row & 7;
        uint4* dst = sA4 + row * 16;
        const float4* sx = (const float4*)(x + (size_t)j * DIN);
        if (h == 0) {
            float4 f[12];
            #pragma unroll
            for (int i = 0; i < 12; i++) f[i] = sx[i];
            #pragma unroll
            for (int c0 = 0; c0 < 6; c0++) {
                uint4 pv;
                pv.x = cvtpk(f[c0 * 2].x, f[c0 * 2].y);
                pv.y = cvtpk(f[c0 * 2].z, f[c0 * 2].w);
                pv.z = cvtpk(f[c0 * 2 + 1].x, f[c0 * 2 + 1].y);
                pv.w = cvtpk(f[c0 * 2 + 1].z, f[c0 * 2 + 1].w);
                dst[c0 ^ xv] = pv;
            }
        } else {
            uint4 z; z.x = z.y = z.z = z.w = 0;
            float4 f[4];
            #pragma unroll
            for (int i = 0; i < 4; i++) f[i] = sx[12 + i];
            float rx = pos[j * 3] - cx, ry = pos[j * 3 + 1] - cy, rz = pos[j * 3 + 2] - cz;
            #pragma unroll
            for (int c0 = 0; c0 < 2; c0++) {
                uint4 pv;
                pv.x = cvtpk(f[c0 * 2].x, f[c0 * 2].y);
                pv.y = cvtpk(f[c0 * 2].z, f[c0 * 2].w);
                pv.z = cvtpk(f[c0 * 2 + 1].x, f[c0 * 2 + 1].y);
                pv.w = cvtpk(f[c0 * 2 + 1].z, f[c0 * 2 + 1].w);
                dst[(6 + c0) ^ xv] = pv;
            }
            uint4 rc; rc.x = cvtpk(rx, ry); rc.y = cvtpk(rz, 0.0f); rc.z = 0; rc.w = 0;
            dst[8 ^ xv] = rc;
            dst[9 ^ xv] = z; dst[10 ^ xv] = z; dst[11 ^ xv] = z;
        }
    }

    int m16 = l & 15, quad = l >> 4;
    int r0 = w * 32;
    const floatx4 vzero = {0.f, 0.f, 0.f, 0.f};

    // per-lane fragment offsets within a 4KB (256-uint4) weight block, one per k-chunk
    int ofs[4];
    #pragma unroll
    for (int ki = 0; ki < 4; ki++) ofs[ki] = (m16 << 4) + ((ki * 4 + quad) ^ (m16 & 7));

// h-epilogue for GEMM1/2: relu(acc+bias) -> bf16 pair writes into swizzled sA rows
#define EPI12(BPTR, S, ACC) { \
    float4 bb = ((const float4*)(BPTR))[(S) * 4 + quad]; \
    _Pragma("unroll") \
    for (int t = 0; t < 2; t++) { \
        int rr = r0 + t * 16 + m16; \
        uint2 pv; \
        pv.x = cvtpk(fmaxf(ACC[t][0] + bb.x, 0.f), fmaxf(ACC[t][1] + bb.y, 0.f)); \
        pv.y = cvtpk(fmaxf(ACC[t][2] + bb.z, 0.f), fmaxf(ACC[t][3] + bb.w, 0.f)); \
        *(uint2*)(smem + rr * 256 + ((((S) * 2 + (quad >> 1)) ^ (rr & 7)) << 4) + ((quad & 1) << 3)) = pv; \
    } }

    // ==== GEMM1: h1 = relu(feat @ W1 + b1), K=96, swapped operands, rolled 8 steps ====
    {
        bf16x8 a1[3][2];
        #pragma unroll
        for (int ki = 0; ki < 3; ki++)
            #pragma unroll
            for (int t = 0; t < 2; t++) {
                int row = r0 + t * 16 + m16;
                a1[ki][t] = __builtin_bit_cast(bf16x8, sA4[row * 16 + ((ki * 4 + quad) ^ (row & 7))]);
            }
        uint4 p0[3], p1[3];
        #pragma unroll
        for (int ki = 0; ki < 3; ki++) {
            if constexpr (WS) { p0[ki] = ws4[ofs[ki]]; p1[ki] = ws4[256 + ofs[ki]]; }
            else { p0[ki] = ldB_fb(W1, 128, m16, ki * 4 + quad, 67);
                   p1[ki] = ldB_fb(W1, 128, 16 + m16, ki * 4 + quad, 67); }
        }
        #pragma unroll 1
        for (int s = 0; s < 8; s += 2) {
            {
                floatx4 acc[2] = {vzero, vzero};
                __builtin_amdgcn_s_setprio(1);
                #pragma unroll
                for (int ki = 0; ki < 3; ki++) {
                    bf16x8 b = __builtin_bit_cast(bf16x8, p0[ki]);
                    #pragma unroll
                    for (int t = 0; t < 2; t++)
                        acc[t] = __builtin_amdgcn_mfma_f32_16x16x32_bf16(b, a1[ki][t], acc[t], 0, 0, 0);
                }
                __builtin_amdgcn_s_setprio(0);
                // prefetch step s+2 (s=6 overfetches into W2 blocks: in-bounds, discarded)
                #pragma unroll
                for (int ki = 0; ki < 3; ki++) {
                    if constexpr (WS) p0[ki] = ws4[(s + 2) * 256 + ofs[ki]];
                    else { int sn = s + 2 < 8 ? s + 2 : 0;
                           p0[ki] = ldB_fb(W1, 128, sn * 16 + m16, ki * 4 + quad, 67); }
                }
                EPI12(b1, s, acc);
            }
            {
                floatx4 acc[2] = {vzero, vzero};
                __builtin_amdgcn_s_setprio(1);
                #pragma unroll
                for (int ki = 0; ki < 3; ki++) {
                    bf16x8 b = __builtin_bit_cast(bf16x8, p1[ki]);
                    #pragma unroll
                    for (int t = 0; t < 2; t++)
                        acc[t] = __builtin_amdgcn_mfma_f32_16x16x32_bf16(b, a1[ki][t], acc[t], 0, 0, 0);
                }
                __builtin_amdgcn_s_setprio(0);
                #pragma unroll
                for (int ki = 0; ki < 3; ki++) {
                    if constexpr (WS) p1[ki] = ws4[(s + 3) * 256 + ofs[ki]];
                    else { int sn = s + 3 < 8 ? s + 3 : 0;
                           p1[ki] = ldB_fb(W1, 128, sn * 16 + m16, ki * 4 + quad, 67); }
                }
                EPI12(b1, s + 1, acc);
            }
        }
    }

    // ==== GEMM2: h2 = relu(h1 @ W2 + b2), K=128, swapped operands, rolled 8 steps ====
    {
        bf16x8 a2[4][2];
        #pragma unroll
        for (int ki = 0; ki < 4; ki++)
            #pragma unroll
            for (int t = 0; t < 2; t++) {
                int row = r0 + t * 16 + m16;
                a2[ki][t] = __builtin_bit_cast(bf16x8, sA4[row * 16 + ((ki * 4 + quad) ^ (row & 7))]);
            }
        const uint4* wp = ws4 + 8 * 256;
        uint4 p0[4], p1[4];
        #pragma unroll
        for (int ki = 0; ki < 4; ki++) {
            if constexpr (WS) { p0[ki] = wp[ofs[ki]]; p1[ki] = wp[256 + ofs[ki]]; }
            else { p0[ki] = ldB_fb(W2, 128, m16, ki * 4 + quad, 128);
                   p1[ki] = ldB_fb(W2, 128, 16 + m16, ki * 4 + quad, 128); }
        }
        #pragma unroll 1
        for (int s = 0; s < 8; s += 2) {
            {
                floatx4 acc[2] = {vzero, vzero};
                __builtin_amdgcn_s_setprio(1);
                #pragma unroll
                for (int ki = 0; ki < 4; ki++) {
                    bf16x8 b = __builtin_bit_cast(bf16x8, p0[ki]);
                    #pragma unroll
                    for (int t = 0; t < 2; t++)
                        acc[t] = __builtin_amdgcn_mfma_f32_16x16x32_bf16(b, a2[ki][t], acc[t], 0, 0, 0);
                }
                __builtin_amdgcn_s_setprio(0);
                #pragma unroll
                for (int ki = 0; ki < 4; ki++) {   // s=6 overfetches into W3: in-bounds
                    if constexpr (WS) p0[ki] = wp[(s + 2) * 256 + ofs[ki]];
                    else { int sn = s + 2 < 8 ? s + 2 : 0;
                           p0[ki] = ldB_fb(W2, 128, sn * 16 + m16, ki * 4 + quad, 128); }
                }
                EPI12(b2, s, acc);
            }
            {
                floatx4 acc[2] = {vzero, vzero};
                __builtin_amdgcn_s_setprio(1);
                #pragma unroll
                for (int ki = 0; ki < 4; ki++) {
                    bf16x8 b = __builtin_bit_cast(bf16x8, p1[ki]);
                    #pragma unroll
                    for (int t = 0; t < 2; t++)
                        acc[t] = __builtin_amdgcn_mfma_f32_16x16x32_bf16(b, a2[ki][t], acc[t], 0, 0, 0);
                }
                __builtin_amdgcn_s_setprio(0);
                #pragma unroll
                for (int ki = 0; ki < 4; ki++) {
                    if constexpr (WS) p1[ki] = wp[(s + 3) * 256 + ofs[ki]];
                    else { int sn = s + 3 < 8 ? s + 3 : 0;
                           p1[ki] = ldB_fb(W2, 128, sn * 16 + m16, ki * 4 + quad, 128); }
                }
                EPI12(b2, s + 1, acc);
            }
        }
    }

// GEMM3 epilogue: unmasked max over this wave's 32 rows (duplicate-padded), then
// bias+relu once (column-constant bias commutes with max; relu is monotone).
#define EPI3(S, ACC) { \
    int col = (S) * 16 + m16; \
    float mv = fmaxf(fmaxf(fmaxf(ACC[0][0], ACC[0][1]), fmaxf(ACC[0][2], ACC[0][3])), \
                     fmaxf(fmaxf(ACC[1][0], ACC[1][1]), fmaxf(ACC[1][2], ACC[1][3]))); \
    mv = fmaxf(mv, __shfl_xor(mv, 16)); \
    mv = fmaxf(mv, __shfl_xor(mv, 32)); \
    mv = fmaxf(mv + b3[col], 0.0f); \
    if (quad == 0) out[(m0 + w) * 256 + col] = mv; }

    // ==== GEMM3: out = maxpool(relu(h2 @ W3 + b3)), K=128, N=256, rolled 16 steps ====
    {
        bf16x8 a3[4][2];
        #pragma unroll
        for (int ki = 0; ki < 4; ki++)
            #pragma unroll
            for (int t = 0; t < 2; t++) {
                int row = r0 + t * 16 + m16;
                a3[ki][t] = __builtin_bit_cast(bf16x8, sA4[row * 16 + ((ki * 4 + quad) ^ (row & 7))]);
            }
        const uint4* wp = ws4 + 16 * 256;
        uint4 p0[4], p1[4];
        #pragma unroll
        for (int ki = 0; ki < 4; ki++) {
            if constexpr (WS) { p0[ki] = wp[ofs[ki]]; p1[ki] = wp[256 + ofs[ki]]; }
            else { p0[ki] = ldB_fb(W3, 256, m16, ki * 4 + quad, 128);
                   p1[ki] = ldB_fb(W3, 256, 16 + m16, ki * 4 + quad, 128); }
        }
        #pragma unroll 1
        for (int s = 0; s < 16; s += 2) {
            int n2 = s + 2 < 16 ? s + 2 : 15;   // clamp: stay inside ws (block <= 31)
            int n3 = s + 3 < 16 ? s + 3 : 15;
            {
                floatx4 acc[2] = {vzero, vzero};
                __builtin_amdgcn_s_setprio(1);
                #pragma unroll
                for (int ki = 0; ki < 4; ki++) {
                    bf16x8 b = __builtin_bit_cast(bf16x8, p0[ki]);
                    #pragma unroll
                    for (int t = 0; t < 2; t++)
                        acc[t] = __builtin_amdgcn_mfma_f32_16x16x32_bf16(a3[ki][t], b, acc[t], 0, 0, 0);
                }
                __builtin_amdgcn_s_setprio(0);
                #pragma unroll
                for (int ki = 0; ki < 4; ki++) {
                    if constexpr (WS) p0[ki] = wp[n2 * 256 + ofs[ki]];
                    else p0[ki] = ldB_fb(W3, 256, n2 * 16 + m16, ki * 4 + quad, 128);
                }
                EPI3(s, acc);
            }
            {
                floatx4 acc[2] = {vzero, vzero};
                __builtin_amdgcn_s_setprio(1);
                #pragma unroll
                for (int ki = 0; ki < 4; ki++) {
                    bf16x8 b = __builtin_bit_cast(bf16x8, p1[ki]);
                    #pragma unroll
                    for (int t = 0; t < 2; t++)
                        acc[t] = __builtin_amdgcn_mfma_f32_16x16x32_bf16(a3[ki][t], b, acc[t], 0, 0, 0);
                }
                __builtin_amdgcn_s_setprio(0);
                #pragma unroll
                for (int ki = 0; ki < 4; ki++) {
                    if constexpr (WS) p1[ki] = wp[n3 * 256 + ofs[ki]];
                    else p1[ki] = ldB_fb(W3, 256, n3 * 16 + m16, ki * 4 + quad, 128);
                }
                EPI3(s + 1, acc);
            }
        }
    }
#undef EPI12
#undef EPI3
}

extern "C" void kernel_launch(void* const* d_in, const int* in_sizes, int n_in,
                              void* d_out, int out_size, void* d_ws, size_t ws_size,
                              hipStream_t stream) {
    const float* x     = (const float*)d_in[0];
    const float* pos   = (const float*)d_in[1];
    const int*   batch = (const int*)d_in[2];
    const int*   idx   = (const int*)d_in[3];
    const float* W1    = (const float*)d_in[4];
    const float* b1    = (const float*)d_in[5];
    const float* W2    = (const float*)d_in[6];
    const float* b2    = (const float*)d_in[7];
    const float* W3    = (const float*)d_in[8];
    const float* b3    = (const float*)d_in[9];
    float* out = (float*)d_out;
    uint4* ws4 = (uint4*)d_ws;

    if (ws_size >= 131072) {
        hipLaunchKernelGGL(prep_kernel, dim3(32), dim3(256), 0, stream, W1, W2, W3, ws4);
        hipLaunchKernelGGL((sa_kernel<true>), dim3(MCENT / WAVES), dim3(512), 0, stream,
                           x, pos, batch, idx, W1, b1, W2, b2, W3, b3, ws4, out);
    } else {
        hipLaunchKernelGGL((sa_kernel<false>), dim3(MCENT / WAVES), dim3(512), 0, stream,
                           x, pos, batch, idx, W1, b1, W2, b2, W3, b3, ws4, out);
    }
}

// Round 11
// 155.232 us; speedup vs baseline: 1.0934x; 1.0934x over previous
//
#include <hip/hip_runtime.h>

// SAModule (PointNet++ SA), fused f32-input kernel. R16 (composition round):
//  - R15 post-mortem: code-size theory wrong (rolled loops 94.5->99.5). Reverted.
//  - R16 = R7 chassis (best measured, 91us: 4-wave/256-thr blocks, 40KB LDS, 16-col
//    double-buffered LDS weight steps, 1-step register prefetch, per-step barrier)
//    + all post-R7 micro-wins, which were only ever measured on slower chassis:
//    * FMA-contracted float4 phase A (R12), lean hit body w/ raw-bit keys (R14)
//    * equalized t^1.5 buckets, histogram built in phase B (R8/R11)
//    * compile-time-unrolled gather + cvtpk bf16 packing (R8/R11)
//    * duplicate-neighbor padding + reduce-then-bias EPI3 (R14)

typedef unsigned short u16;
typedef unsigned int u32;
typedef unsigned long long u64;
typedef __bf16 bf16x8 __attribute__((ext_vector_type(8)));
typedef float floatx4 __attribute__((ext_vector_type(4)));

#define PCLOUD 4096
#define DIN    64
#define MCENT  8192
#define KNBR   32
#define CAP    448

// smem map (40960 B): sA = [0,32768) 128 rows x 256B; sW dbuf = [32768,40960) 2 x 4KB.
// phase A/B overlay inside the sA region (dead before gather writes sA):
#define OFF_LIST  0        // u64[4][CAP] = 14336
#define OFF_HIST  14336    // u32[4][32]  = 512
#define OFF_NBRL  14848    // int[4][32]  = 512
#define OFF_CNT   15360    // int[4] acnt | int[4] cnt2
#define OFF_CEN   15392    // float4[4] centers (x,y,z,|c|^2)
#define OFF_BCL   15456    // int[4] cloud ids

__device__ inline u16 f2bf(float f) {          // RNE, no scrub (inputs finite)
    u32 b = __float_as_uint(f);
    b += 0x7fffu + ((b >> 16) & 1u);
    return (u16)(b >> 16);
}
__device__ inline u32 cvtpk(float a, float b) {  // packed {bf16(a), bf16(b)<<16}, RNE
    u32 r;
    asm("v_cvt_pk_bf16_f32 %0, %1, %2" : "=v"(r) : "v"(a), "v"(b));
    return r;
}
__device__ inline u64 wave_min_u64(u64 v) {
    #pragma unroll
    for (int off = 32; off; off >>= 1) {
        u64 o = __shfl_xor((unsigned long long)v, off);
        if (o < v) v = o;
    }
    return v;
}
// density-equalized bucket over raw-bits keys (d2 >= 0): count/bucket ~ const, monotone.
__device__ inline int key_bucket(u64 k) {
    float d2 = __uint_as_float((u32)(k >> 32));
    float t = d2 * 25.0f;                              // d2/R2, [0,1]
    float b = 32.0f * t * __builtin_sqrtf(t);          // 32 * t^1.5
    int bi = (int)b;
    return bi > 31 ? 31 : bi;
}

// ---- prep: weights -> bf16 B-fragment images in ws (exact LDS bit layout) ----
// ws = 32 contiguous 4KB step blocks of 16 cols each: 0..7 W1, 8..15 W2, 16..31 W3.
// blk layout (256 uint4): chunk[n*16 + (kc^(n&7))] = {bf16 W[kc*8+j][col0+n], j=0..7}
__global__ void prep_kernel(const float* __restrict__ W1, const float* __restrict__ W2,
                            const float* __restrict__ W3, uint4* __restrict__ ws) {
    int t = blockIdx.x * 256 + threadIdx.x;   // 0..8191
    int g = t >> 11, r = t & 2047;
    int n = r >> 4, kc = r & 15;
    const float* W; int rs, n0, krows;
    if (g == 0)      { W = W1; rs = 128; n0 = 0;   krows = 67;  }
    else if (g == 1) { W = W2; rs = 128; n0 = 0;   krows = 128; }
    else if (g == 2) { W = W3; rs = 256; n0 = 0;   krows = 128; }
    else             { W = W3; rs = 256; n0 = 128; krows = 128; }
    u16 e[8];
    #pragma unroll
    for (int j = 0; j < 8; j++) {
        int k = kc * 8 + j;
        e[j] = (k < krows) ? f2bf(W[(size_t)k * rs + n0 + n]) : (u16)0;
    }
    ws[(g << 11) + (n << 4) + (kc ^ (n & 7))] = *(const uint4*)e;
}

// Commit one 4KB weight step into a buffer. WS: linear b128 write of the preloaded reg.
// !WS fallback: compute the bf16 packing on the fly (correctness path, no workspace).
template <bool WS>
__device__ __forceinline__ void commitW(int s, uint4 ld, uint4* __restrict__ buf, int tid,
                                        const float* __restrict__ W1,
                                        const float* __restrict__ W2,
                                        const float* __restrict__ W3) {
    if constexpr (WS) {
        buf[tid] = ld;
    } else {
        const float* W; int rs, n0, krows;
        if (s < 8)       { W = W1; rs = 128; n0 = s * 16;        krows = 67;  }
        else if (s < 16) { W = W2; rs = 128; n0 = (s - 8) * 16;  krows = 128; }
        else             { W = W3; rs = 256; n0 = (s - 16) * 16; krows = 128; }
        int n = tid >> 4, kc = tid & 15;
        u16 e[8];
        #pragma unroll
        for (int j = 0; j < 8; j++) {
            int k = kc * 8 + j;
            e[j] = (k < krows) ? f2bf(W[(size_t)k * rs + n0 + n]) : (u16)0;
        }
        buf[(n << 4) + (kc ^ (n & 7))] = *(const uint4*)e;
    }
}

// Lean hit push: clamp d2>=0 (self-point FMA noise), raw-bits monotone key.
__device__ __forceinline__ void push_hit(int c, float d2, int j,
                                         int* acnt, u64* lists) {
    int p = atomicAdd(&acnt[c], 1);
    u64 key = ((u64)__float_as_uint(fmaxf(d2, 0.0f)) << 32) | (u32)j;
    if (p < CAP) lists[c * CAP + p] = key;
}

template <bool WS>
__global__ __launch_bounds__(256, 4) void sa_kernel(
    const float* __restrict__ x, const float* __restrict__ pos,
    const int* __restrict__ batch, const int* __restrict__ idx,
    const float* __restrict__ W1, const float* __restrict__ b1,
    const float* __restrict__ W2, const float* __restrict__ b2,
    const float* __restrict__ W3, const float* __restrict__ b3,
    const uint4* __restrict__ ws4, float* __restrict__ out) {
    __shared__ __align__(16) char smem[40960];
    u64*  lists = (u64*)(smem + OFF_LIST);
    u32*  hist  = (u32*)(smem + OFF_HIST);
    int*  nbrl  = (int*)(smem + OFF_NBRL);
    int*  acnt  = (int*)(smem + OFF_CNT);
    int*  cnt2  = (int*)(smem + OFF_CNT + 16);
    float4* cen = (float4*)(smem + OFF_CEN);
    int*  bcls  = (int*)(smem + OFF_BCL);
    uint4* sA4  = (uint4*)smem;
    uint4* sWb0 = (uint4*)(smem + 32768);
    uint4* sWb1 = (uint4*)(smem + 36864);

    int tid = threadIdx.x, w = tid >> 6, l = tid & 63;
    int bid = blockIdx.x;
    int m0 = ((bid & 7) << 10) + ((bid >> 3) << 2);   // XCD-friendly: bid%8 ~ cloud
    int m = m0 + w;
    int ic = idx[m] & (8 * PCLOUD - 1);
    float cx = pos[ic * 3], cy = pos[ic * 3 + 1], cz = pos[ic * 3 + 2];
    float sc = __fadd_rn(__fadd_rn(__fmul_rn(cx, cx), __fmul_rn(cy, cy)), __fmul_rn(cz, cz));
    int bcl = batch[ic] & 7;
    int base = bcl << 12;
    const float R2 = 0.04f;

    if (l == 0) { cen[w] = make_float4(cx, cy, cz, sc); bcls[w] = bcl; }
    if (tid < 4) { acnt[tid] = 0; cnt2[tid] = 0; }
    if (l == 1) {
        float* o1 = out + MCENT * 256;
        o1[m * 3] = cx; o1[m * 3 + 1] = cy; o1[m * 3 + 2] = cz;
        (o1 + MCENT * 3)[m] = (float)bcl;
    }
    __syncthreads();

    // ---- phase A: cooperative scan, float4 loads, FMA-contracted tests vs 4 centers ----
    bool uni = (bcls[0] == bcls[1]) && (bcls[1] == bcls[2]) && (bcls[2] == bcls[3]);
    if (uni) {
        float4 cA = cen[0], cB = cen[1], cC = cen[2], cD = cen[3];
        float nAx = -2.0f * cA.x, nAy = -2.0f * cA.y, nAz = -2.0f * cA.z;
        float nBx = -2.0f * cB.x, nBy = -2.0f * cB.y, nBz = -2.0f * cB.z;
        float nCx = -2.0f * cC.x, nCy = -2.0f * cC.y, nCz = -2.0f * cC.z;
        float nDx = -2.0f * cD.x, nDy = -2.0f * cD.y, nDz = -2.0f * cD.z;
        int jb = bcls[0] << 12;
        const float4* pb4 = (const float4*)(pos + (size_t)jb * 3);

#define TEST1(NX, NY, NZ, SW, CI, SP, PX, PY, PZ, J) { \
    float d2 = __builtin_fmaf((NX), (PX), __builtin_fmaf((NY), (PY), \
               __builtin_fmaf((NZ), (PZ), (SW) + (SP)))); \
    if (d2 <= R2) push_hit(CI, d2, J, acnt, lists); }
#define TESTP(PX, PY, PZ, J) { \
    float sp = __builtin_fmaf((PX), (PX), __builtin_fmaf((PY), (PY), (PZ) * (PZ))); \
    TEST1(nAx, nAy, nAz, cA.w, 0, sp, PX, PY, PZ, J) \
    TEST1(nBx, nBy, nBz, cB.w, 1, sp, PX, PY, PZ, J) \
    TEST1(nCx, nCy, nCz, cC.w, 2, sp, PX, PY, PZ, J) \
    TEST1(nDx, nDy, nDz, cD.w, 3, sp, PX, PY, PZ, J) }

        #pragma unroll
        for (int it = 0; it < 4; it++) {
            int tq = it * 256 + tid;                   // quad-point index 0..1023
            float4 q0 = pb4[tq * 3], q1 = pb4[tq * 3 + 1], q2 = pb4[tq * 3 + 2];
            int j0 = jb + tq * 4;
            TESTP(q0.x, q0.y, q0.z, j0)
            TESTP(q0.w, q1.x, q1.y, j0 + 1)
            TESTP(q1.z, q1.w, q2.x, j0 + 2)
            TESTP(q2.y, q2.z, q2.w, j0 + 3)
        }
#undef TESTP
#undef TEST1
    } else {
        // rare mixed-cloud block: per-wave scan of own cloud from global (FMA form)
        float nx = -2.0f * cx, ny = -2.0f * cy, nz = -2.0f * cz;
        for (int t = l; t < PCLOUD; t += 64) {
            int j = base + t;
            float px = pos[j * 3], py = pos[j * 3 + 1], pz = pos[j * 3 + 2];
            float sp = __builtin_fmaf(px, px, __builtin_fmaf(py, py, pz * pz));
            float d2 = __builtin_fmaf(nx, px, __builtin_fmaf(ny, py,
                       __builtin_fmaf(nz, pz, sc + sp)));
            if (d2 <= R2) push_hit(w, d2, j, acnt, lists);
        }
    }
    __syncthreads();   // cross-wave list visibility

    int c = acnt[w];
    u64* mylist = lists + w * CAP;

    // ---- phase B: select the 32 smallest (d2,idx) keys (set only; order free) ----
    int selj = -1;
    if (c <= KNBR) {
        if (l < c) selj = (int)(u32)mylist[l];
    } else if (c <= CAP) {
        u64 kk[7];
        int bk[7];
        if (l < 32) hist[w * 32 + l] = 0;              // same-wave LDS: ordered
        #pragma unroll
        for (int i = 0; i < 7; i++) kk[i] = (l + i * 64 < c) ? mylist[l + i * 64] : ~0ull;
        #pragma unroll
        for (int i = 0; i < 7; i++) {                  // build d2 histogram (this wave only)
            bk[i] = 32;
            if (kk[i] != ~0ull) {
                bk[i] = key_bucket(kk[i]);
                atomicAdd(&hist[w * 32 + bk[i]], 1u);
            }
        }
        int hv = (l < 32) ? (int)hist[w * 32 + l] : 0; // atomics above are same-wave: ordered
        #pragma unroll
        for (int off = 1; off <= 16; off <<= 1) {   // inclusive scan, lanes 0..31
            int o = __shfl_up(hv, off);
            if (l >= off) hv += o;
        }
        u64 ge = __ballot((l < 32) && (hv >= KNBR));
        int B = __ffsll((unsigned long long)ge) - 1;        // threshold bucket
        int S = (B == 0) ? 0 : __shfl(hv, B - 1);           // count strictly below B
        #pragma unroll
        for (int i = 0; i < 7; i++) {                       // bulk-select below B
            if (kk[i] != ~0ull) {
                if (bk[i] < B) { int p = atomicAdd(&cnt2[w], 1); nbrl[w * 32 + p] = (int)(u32)kk[i]; }
                if (bk[i] != B) kk[i] = ~0ull;              // keep only bucket-B keys
            }
        }
        int need = KNBR - S;                                // equalized buckets: ~1-4 rounds
        u64 last = 0;
        for (int r = 0; r < need; r++) {
            u64 mn = ~0ull;
            #pragma unroll
            for (int i = 0; i < 7; i++) if (kk[i] > last && kk[i] < mn) mn = kk[i];
            mn = wave_min_u64(mn);
            if (l == 0) nbrl[w * 32 + S + r] = (int)(u32)mn;
            last = mn;
        }
        if (l < KNBR) selj = nbrl[w * 32 + l];
    } else {
        // overflow fallback (never taken for uniform data): streaming 32-round argmin
        float nx = -2.0f * cx, ny = -2.0f * cy, nz = -2.0f * cz;
        u64 last = 0;
        for (int r = 0; r < KNBR; r++) {
            u64 mn = ~0ull;
            for (int t = l; t < PCLOUD; t += 64) {
                int j = base + t;
                float px = pos[j * 3], py = pos[j * 3 + 1], pz = pos[j * 3 + 2];
                float sp = __builtin_fmaf(px, px, __builtin_fmaf(py, py, pz * pz));
                float d2 = __builtin_fmaf(nx, px, __builtin_fmaf(ny, py,
                           __builtin_fmaf(nz, pz, sc + sp)));
                if (d2 <= R2) {
                    u64 kf = ((u64)__float_as_uint(fmaxf(d2, 0.0f)) << 32) | (u32)j;
                    if (kf > last && kf < mn) mn = kf;
                }
            }
            mn = wave_min_u64(mn);
            if (l == r) selj = (int)(u32)mn;
            last = mn;
        }
    }
    // duplicate-pad: rows beyond the valid count take lane-0's neighbor (MAX-invariant;
    // c>=1 always since the center is in its own ball).
    {
        int s0 = __shfl(selj, 0);
        if (selj < 0) selj = s0;
    }
    __syncthreads();   // lists/hist dead; sA becomes the GEMM A-tile; sW staging begins

    uint4 ld = {};
    if constexpr (WS) ld = ws4[tid];                       // load step 0

    // ---- gather 32 feat rows per wave (XOR 16B-chunk swizzle); rows are wave-private.
    //      All rows valid (duplicate-padded); h-branched compile-time unroll.
    {
        int h = l & 1, rl = l >> 1;
        int row = w * 32 + rl;
        int j = __shfl(selj, rl);
        int xv = row & 7;
        uint4* dst = sA4 + row * 16;
        const float4* sx = (const float4*)(x + (size_t)j * DIN);
        if (h == 0) {
            float4 f[12];
            #pragma unroll
            for (int i = 0; i < 12; i++) f[i] = sx[i];
            #pragma unroll
            for (int c0 = 0; c0 < 6; c0++) {
                uint4 pv;
                pv.x = cvtpk(f[c0 * 2].x, f[c0 * 2].y);
                pv.y = cvtpk(f[c0 * 2].z, f[c0 * 2].w);
                pv.z = cvtpk(f[c0 * 2 + 1].x, f[c0 * 2 + 1].y);
                pv.w = cvtpk(f[c0 * 2 + 1].z, f[c0 * 2 + 1].w);
                dst[c0 ^ xv] = pv;
            }
        } else {
            uint4 z; z.x = z.y = z.z = z.w = 0;
            float4 f[4];
            #pragma unroll
            for (int i = 0; i < 4; i++) f[i] = sx[12 + i];
            float rx = pos[j * 3] - cx, ry = pos[j * 3 + 1] - cy, rz = pos[j * 3 + 2] - cz;
            #pragma unroll
            for (int c0 = 0; c0 < 2; c0++) {
                uint4 pv;
                pv.x = cvtpk(f[c0 * 2].x, f[c0 * 2].y);
                pv.y = cvtpk(f[c0 * 2].z, f[c0 * 2].w);
                pv.z = cvtpk(f[c0 * 2 + 1].x, f[c0 * 2 + 1].y);
                pv.w = cvtpk(f[c0 * 2 + 1].z, f[c0 * 2 + 1].w);
                dst[(6 + c0) ^ xv] = pv;
            }
            uint4 rc; rc.x = cvtpk(rx, ry); rc.y = cvtpk(rz, 0.0f); rc.z = 0; rc.w = 0;
            dst[8 ^ xv] = rc;
            dst[9 ^ xv] = z; dst[10 ^ xv] = z; dst[11 ^ xv] = z;
        }
    }
    commitW<WS>(0, ld, sWb0, tid, W1, W2, W3);
    if constexpr (WS) ld = ws4[256 + tid];                 // load step 1
    __syncthreads();

    int m16 = l & 15, quad = l >> 4;
    int r0 = w * 32;
    const floatx4 vzero = {0.f, 0.f, 0.f, 0.f};

    // ======== GEMM1: h1 = relu(feat @ W1 + b1), K=96, swapped operands, 8 N-steps ========
    {
        bf16x8 a1[3][2];
        #pragma unroll
        for (int ki = 0; ki < 3; ki++)
            #pragma unroll
            for (int t = 0; t < 2; t++) {
                int row = r0 + t * 16 + m16;
                a1[ki][t] = __builtin_bit_cast(bf16x8, sA4[row * 16 + ((ki * 4 + quad) ^ (row & 7))]);
            }
        #pragma unroll 2
        for (int s = 0; s < 8; s++) {
            uint4* buf  = (s & 1) ? sWb1 : sWb0;
            uint4* nbuf = (s & 1) ? sWb0 : sWb1;
            floatx4 acc[2] = {vzero, vzero};
            __builtin_amdgcn_s_setprio(1);
            #pragma unroll
            for (int ki = 0; ki < 3; ki++) {
                bf16x8 b = __builtin_bit_cast(bf16x8, buf[(m16 << 4) + ((ki * 4 + quad) ^ (m16 & 7))]);
                #pragma unroll
                for (int t = 0; t < 2; t++)
                    acc[t] = __builtin_amdgcn_mfma_f32_16x16x32_bf16(b, a1[ki][t], acc[t], 0, 0, 0);
            }
            __builtin_amdgcn_s_setprio(0);
            float4 bb = ((const float4*)b1)[s * 4 + quad];  // cols s*16+quad*4..+3
            #pragma unroll
            for (int t = 0; t < 2; t++) {
                int rr = r0 + t * 16 + m16;
                uint2 pv;
                pv.x = cvtpk(fmaxf(acc[t][0] + bb.x, 0.f), fmaxf(acc[t][1] + bb.y, 0.f));
                pv.y = cvtpk(fmaxf(acc[t][2] + bb.z, 0.f), fmaxf(acc[t][3] + bb.w, 0.f));
                *(uint2*)(smem + rr * 256 + (((s * 2 + (quad >> 1)) ^ (rr & 7)) << 4) + ((quad & 1) << 3)) = pv;
            }
            commitW<WS>(s + 1, ld, nbuf, tid, W1, W2, W3);
            if constexpr (WS) ld = ws4[(s + 2) * 256 + tid];
            __syncthreads();
        }
    }

    // ======== GEMM2: h2 = relu(h1 @ W2 + b2), K=128, swapped operands, 8 N-steps ========
    {
        bf16x8 a2[4][2];
        #pragma unroll
        for (int ki = 0; ki < 4; ki++)
            #pragma unroll
            for (int t = 0; t < 2; t++) {
                int row = r0 + t * 16 + m16;
                a2[ki][t] = __builtin_bit_cast(bf16x8, sA4[row * 16 + ((ki * 4 + quad) ^ (row & 7))]);
            }
        #pragma unroll 2
        for (int s = 0; s < 8; s++) {
            uint4* buf  = (s & 1) ? sWb1 : sWb0;
            uint4* nbuf = (s & 1) ? sWb0 : sWb1;
            floatx4 acc[2] = {vzero, vzero};
            __builtin_amdgcn_s_setprio(1);
            #pragma unroll
            for (int ki = 0; ki < 4; ki++) {
                bf16x8 b = __builtin_bit_cast(bf16x8, buf[(m16 << 4) + ((ki * 4 + quad) ^ (m16 & 7))]);
                #pragma unroll
                for (int t = 0; t < 2; t++)
                    acc[t] = __builtin_amdgcn_mfma_f32_16x16x32_bf16(b, a2[ki][t], acc[t], 0, 0, 0);
            }
            __builtin_amdgcn_s_setprio(0);
            float4 bb = ((const float4*)b2)[s * 4 + quad];
            #pragma unroll
            for (int t = 0; t < 2; t++) {
                int rr = r0 + t * 16 + m16;
                uint2 pv;
                pv.x = cvtpk(fmaxf(acc[t][0] + bb.x, 0.f), fmaxf(acc[t][1] + bb.y, 0.f));
                pv.y = cvtpk(fmaxf(acc[t][2] + bb.z, 0.f), fmaxf(acc[t][3] + bb.w, 0.f));
                *(uint2*)(smem + rr * 256 + (((s * 2 + (quad >> 1)) ^ (rr & 7)) << 4) + ((quad & 1) << 3)) = pv;
            }
            commitW<WS>(s + 9, ld, nbuf, tid, W1, W2, W3);
            if constexpr (WS) ld = ws4[(s + 10) * 256 + tid];
            __syncthreads();
        }
    }

    // ==== GEMM3: out = maxpool(relu(h2 @ W3 + b3)), K=128, N=256, 16 N-steps ====
    {
        bf16x8 a3[4][2];
        #pragma unroll
        for (int ki = 0; ki < 4; ki++)
            #pragma unroll
            for (int t = 0; t < 2; t++) {
                int row = r0 + t * 16 + m16;
                a3[ki][t] = __builtin_bit_cast(bf16x8, sA4[row * 16 + ((ki * 4 + quad) ^ (row & 7))]);
            }
        #pragma unroll 2
        for (int s = 0; s < 16; s++) {
            uint4* buf  = (s & 1) ? sWb1 : sWb0;
            uint4* nbuf = (s & 1) ? sWb0 : sWb1;
            floatx4 acc[2] = {vzero, vzero};
            __builtin_amdgcn_s_setprio(1);
            #pragma unroll
            for (int ki = 0; ki < 4; ki++) {
                bf16x8 b = __builtin_bit_cast(bf16x8, buf[(m16 << 4) + ((ki * 4 + quad) ^ (m16 & 7))]);
                #pragma unroll
                for (int t = 0; t < 2; t++)
                    acc[t] = __builtin_amdgcn_mfma_f32_16x16x32_bf16(a3[ki][t], b, acc[t], 0, 0, 0);
            }
            __builtin_amdgcn_s_setprio(0);
            // unmasked max (duplicate-padded rows), then bias+relu once:
            // column-constant bias commutes with max; relu is monotone.
            int col = s * 16 + m16;
            float mv = fmaxf(fmaxf(fmaxf(acc[0][0], acc[0][1]), fmaxf(acc[0][2], acc[0][3])),
                             fmaxf(fmaxf(acc[1][0], acc[1][1]), fmaxf(acc[1][2], acc[1][3])));
            mv = fmaxf(mv, __shfl_xor(mv, 16));
            mv = fmaxf(mv, __shfl_xor(mv, 32));
            mv = fmaxf(mv + b3[col], 0.0f);
            if (quad == 0) out[(m0 + w) * 256 + col] = mv;
            if (s < 15) {
                commitW<WS>(s + 17, ld, nbuf, tid, W1, W2, W3);
                if constexpr (WS) { if (s < 14) ld = ws4[(s + 18) * 256 + tid]; }
                __syncthreads();
            }
        }
    }
}

extern "C" void kernel_launch(void* const* d_in, const int* in_sizes, int n_in,
                              void* d_out, int out_size, void* d_ws, size_t ws_size,
                              hipStream_t stream) {
    const float* x     = (const float*)d_in[0];
    const float* pos   = (const float*)d_in[1];
    const int*   batch = (const int*)d_in[2];
    const int*   idx   = (const int*)d_in[3];
    const float* W1    = (const float*)d_in[4];
    const float* b1    = (const float*)d_in[5];
    const float* W2    = (const float*)d_in[6];
    const float* b2    = (const float*)d_in[7];
    const float* W3    = (const float*)d_in[8];
    const float* b3    = (const float*)d_in[9];
    float* out = (float*)d_out;
    uint4* ws4 = (uint4*)d_ws;

    if (ws_size >= 131072) {
        hipLaunchKernelGGL(prep_kernel, dim3(32), dim3(256), 0, stream, W1, W2, W3, ws4);
        hipLaunchKernelGGL((sa_kernel<true>), dim3(MCENT / 4), dim3(256), 0, stream,
                           x, pos, batch, idx, W1, b1, W2, b2, W3, b3, ws4, out);
    } else {
        hipLaunchKernelGGL((sa_kernel<false>), dim3(MCENT / 4), dim3(256), 0, stream,
                           x, pos, batch, idx, W1, b1, W2, b2, W3, b3, ws4, out);
    }
}